// Round 1
// baseline (1552.705 us; speedup 1.0000x reference)
//
#include <hip/hip_runtime.h>

// ---------------------------------------------------------------------------
// MatGCN: 4-layer GCN (D=128) + LN + residual + mean-pool + linear head.
// Strategy: build CSR (by dst) per launch -> atomic-free per-node gather with
// fused self-loop/bias/LayerNorm/residual/ReLU. fp32 throughout.
// ---------------------------------------------------------------------------

__global__ void k_hist(const int* __restrict__ dst, int* __restrict__ cnt, int E) {
    int e = blockIdx.x * blockDim.x + threadIdx.x;
    if (e < E) atomicAdd(&cnt[dst[e]], 1);
}

__global__ void k_dis(const int* __restrict__ cnt, float* __restrict__ dis, int n) {
    int i = blockIdx.x * blockDim.x + threadIdx.x;
    if (i < n) dis[i] = rsqrtf((float)cnt[i] + 1.0f);
}

// single-block chunked exclusive scan over n entries (n ~ 100K -> ~98 chunks)
__global__ __launch_bounds__(1024) void k_scan(const int* __restrict__ cnt,
                                               int* __restrict__ row_off,
                                               int* __restrict__ cursor, int n) {
    __shared__ int s[1024];
    int tid = threadIdx.x;
    int carry = 0;
    for (int base = 0; base < n; base += 1024) {
        int i = base + tid;
        int v = (i < n) ? cnt[i] : 0;
        s[tid] = v;
        __syncthreads();
        for (int off = 1; off < 1024; off <<= 1) {
            int t = (tid >= off) ? s[tid - off] : 0;
            __syncthreads();
            s[tid] += t;
            __syncthreads();
        }
        int excl = carry + s[tid] - v;
        if (i < n) { row_off[i] = excl; cursor[i] = excl; }
        carry += s[1023];
        __syncthreads();
    }
    if (tid == 0) row_off[n] = carry;
}

__global__ void k_reorder(const int* __restrict__ src, const int* __restrict__ dst,
                          int* __restrict__ cursor, int* __restrict__ col,
                          float* __restrict__ coefs, const float* __restrict__ dis, int E) {
    int e = blockIdx.x * blockDim.x + threadIdx.x;
    if (e < E) {
        int d = dst[e], s = src[e];
        int p = atomicAdd(&cursor[d], 1);
        col[p] = s;
        coefs[p] = dis[s] * dis[d];
    }
}

// H = X @ W  (X:[n,128], W:[128,128]). Block: 256 thr, 64 rows; thread tile 8x4.
// X tile staged in LDS (32KB); W rows read from global (L1/L2-resident, 64KB total).
__global__ __launch_bounds__(256) void k_matmul(const float* __restrict__ X,
                                                const float* __restrict__ W,
                                                float* __restrict__ H, int n) {
    __shared__ float sX[64 * 128];
    const int tid = threadIdx.x;
    const int row0 = blockIdx.x * 64;
    for (int i = tid; i < 2048; i += 256) {       // 2048 float4 = 64x128 floats
        int r = i >> 5;
        int gr = row0 + r;
        float4 v = make_float4(0.f, 0.f, 0.f, 0.f);
        if (gr < n) v = ((const float4*)(X + (size_t)gr * 128))[i & 31];
        ((float4*)sX)[i] = v;
    }
    __syncthreads();
    const int rg = tid >> 5;     // 8 row-groups of 8 rows
    const int cg = tid & 31;     // 32 col-groups of 4 cols
    const int r0 = rg * 8;
    const int c0 = cg * 4;
    float acc[8][4];
#pragma unroll
    for (int i = 0; i < 8; i++)
#pragma unroll
        for (int j = 0; j < 4; j++) acc[i][j] = 0.f;

    for (int k = 0; k < 128; k += 4) {
        float4 b0 = *(const float4*)(W + (size_t)(k + 0) * 128 + c0);
        float4 b1 = *(const float4*)(W + (size_t)(k + 1) * 128 + c0);
        float4 b2 = *(const float4*)(W + (size_t)(k + 2) * 128 + c0);
        float4 b3 = *(const float4*)(W + (size_t)(k + 3) * 128 + c0);
#pragma unroll
        for (int i = 0; i < 8; i++) {
            float4 a = *(const float4*)&sX[(r0 + i) * 128 + k];
            acc[i][0] += a.x * b0.x + a.y * b1.x + a.z * b2.x + a.w * b3.x;
            acc[i][1] += a.x * b0.y + a.y * b1.y + a.z * b2.y + a.w * b3.y;
            acc[i][2] += a.x * b0.z + a.y * b1.z + a.z * b2.z + a.w * b3.z;
            acc[i][3] += a.x * b0.w + a.y * b1.w + a.z * b2.w + a.w * b3.w;
        }
    }
#pragma unroll
    for (int i = 0; i < 8; i++) {
        int gr = row0 + r0 + i;
        if (gr < n)
            *(float4*)(H + (size_t)gr * 128 + c0) =
                make_float4(acc[i][0], acc[i][1], acc[i][2], acc[i][3]);
    }
}

// One 128-thread block per node: CSR gather + self-loop + bias + LN (+res)(+relu)
__global__ __launch_bounds__(128) void k_node(const float* __restrict__ H,
                                              float* __restrict__ Xio,
                                              const int* __restrict__ row_off,
                                              const int* __restrict__ col,
                                              const float* __restrict__ coefs,
                                              const float* __restrict__ dis,
                                              const float* __restrict__ bias,
                                              const float* __restrict__ gamma,
                                              const float* __restrict__ beta,
                                              int do_relu, int do_res) {
    const int node = blockIdx.x;
    const int d = threadIdx.x;
    const int e0 = row_off[node];
    const int e1 = row_off[node + 1];
    float acc = 0.f;
    for (int e = e0; e < e1; e++) {
        int s = col[e];
        float c = coefs[e];
        acc += H[(size_t)s * 128 + d] * c;
    }
    float dn = dis[node];
    acc += H[(size_t)node * 128 + d] * (dn * dn);
    acc += bias[d];

    __shared__ float red[2];
    float v = acc;
    float t = v;
#pragma unroll
    for (int off = 32; off > 0; off >>= 1) t += __shfl_down(t, off, 64);
    if ((d & 63) == 0) red[d >> 6] = t;
    __syncthreads();
    float mu = (red[0] + red[1]) * (1.f / 128.f);
    __syncthreads();
    float xm = v - mu;
    t = xm * xm;
#pragma unroll
    for (int off = 32; off > 0; off >>= 1) t += __shfl_down(t, off, 64);
    if ((d & 63) == 0) red[d >> 6] = t;
    __syncthreads();
    float var = (red[0] + red[1]) * (1.f / 128.f);
    float y = xm * rsqrtf(var + 1e-5f) * gamma[d] + beta[d];
    if (do_res) y += Xio[(size_t)node * 128 + d];
    if (do_relu) y = fmaxf(y, 0.f);
    Xio[(size_t)node * 128 + d] = y;
}

// One 128-thread block per graph: binary-search segment in sorted batch,
// mean-pool, fused linear head.
__global__ __launch_bounds__(128) void k_pool(const float* __restrict__ X,
                                              const int* __restrict__ batch,
                                              const float* __restrict__ lin_w,
                                              const float* __restrict__ lin_b,
                                              float* __restrict__ out, int n) {
    int g = blockIdx.x;
    int d = threadIdx.x;
    int lo = 0, hi = n;
    while (lo < hi) { int m = (lo + hi) >> 1; if (batch[m] < g) lo = m + 1; else hi = m; }
    int start = lo;
    hi = n;
    while (lo < hi) { int m = (lo + hi) >> 1; if (batch[m] <= g) lo = m + 1; else hi = m; }
    int end = lo;
    float s = 0.f;
    for (int i = start; i < end; i++) s += X[(size_t)i * 128 + d];
    float cntf = (float)(end - start);
    float mean = s / fmaxf(cntf, 1.f);
    float p = mean * lin_w[d];
    __shared__ float red[2];
#pragma unroll
    for (int off = 32; off > 0; off >>= 1) p += __shfl_down(p, off, 64);
    if ((d & 63) == 0) red[d >> 6] = p;
    __syncthreads();
    if (d == 0) out[g] = red[0] + red[1] + lin_b[0];
}

extern "C" void kernel_launch(void* const* d_in, const int* in_sizes, int n_in,
                              void* d_out, int out_size, void* d_ws, size_t ws_size,
                              hipStream_t stream) {
    const float* x      = (const float*)d_in[0];
    const int*   eidx   = (const int*)d_in[1];
    const int*   batch  = (const int*)d_in[2];
    const float* Ws     = (const float*)d_in[3];
    const float* bs     = (const float*)d_in[4];
    const float* gammas = (const float*)d_in[5];
    const float* betas  = (const float*)d_in[6];
    const float* lin_w  = (const float*)d_in[7];
    const float* lin_b  = (const float*)d_in[8];
    float* out = (float*)d_out;

    const int n = in_sizes[2];        // 100000 nodes
    const int E = in_sizes[1] / 2;    // 1600000 edges
    const int G = out_size;           // 512 graphs

    const int* src  = eidx;
    const int* dstp = eidx + E;

    char* w = (char*)d_ws;
    size_t off = 0;
    auto alloc = [&](size_t bytes) {
        void* p = w + off;
        off = (off + bytes + 15) & ~(size_t)15;
        return p;
    };
    int*   cnt     = (int*)  alloc((size_t)n * 4);
    int*   row_off = (int*)  alloc((size_t)(n + 1) * 4);
    int*   cursor  = (int*)  alloc((size_t)n * 4);
    float* dis     = (float*)alloc((size_t)n * 4);
    int*   col     = (int*)  alloc((size_t)E * 4);
    float* coefs   = (float*)alloc((size_t)E * 4);
    float* h       = (float*)alloc((size_t)n * 128 * 4);
    float* xc      = (float*)alloc((size_t)n * 128 * 4);
    (void)ws_size; (void)n_in;

    hipMemsetAsync(cnt, 0, (size_t)n * 4, stream);
    k_hist<<<(E + 255) / 256, 256, 0, stream>>>(dstp, cnt, E);
    k_dis<<<(n + 255) / 256, 256, 0, stream>>>(cnt, dis, n);
    k_scan<<<1, 1024, 0, stream>>>(cnt, row_off, cursor, n);
    k_reorder<<<(E + 255) / 256, 256, 0, stream>>>(src, dstp, cursor, col, coefs, dis, E);

    for (int layer = 0; layer < 4; layer++) {
        const float* xin = (layer == 0) ? x : xc;
        k_matmul<<<(n + 63) / 64, 256, 0, stream>>>(xin, Ws + (size_t)layer * 128 * 128, h, n);
        k_node<<<n, 128, 0, stream>>>(h, xc, row_off, col, coefs, dis,
                                      bs + (size_t)layer * 128,
                                      gammas + (size_t)layer * 128,
                                      betas + (size_t)layer * 128,
                                      (layer < 3) ? 1 : 0, (layer > 0) ? 1 : 0);
    }
    k_pool<<<G, 128, 0, stream>>>(xc, batch, lin_w, lin_b, out, n);
}

// Round 2
// 938.299 us; speedup vs baseline: 1.6548x; 1.6548x over previous
//
#include <hip/hip_runtime.h>
#include <hip/hip_bf16.h>

// ---------------------------------------------------------------------------
// MatGCN: 4-layer GCN (D=128) + LN + residual + mean-pool + linear head.
// R2: bf16 message storage (halves gather bytes), wave-per-node gather with
// 4-way unrolled independent loads (MLP), hierarchical scan.
// ---------------------------------------------------------------------------

typedef __hip_bfloat162 bf2;

__global__ void k_hist(const int* __restrict__ dst, int* __restrict__ cnt, int E) {
    int e = blockIdx.x * blockDim.x + threadIdx.x;
    if (e < E) atomicAdd(&cnt[dst[e]], 1);
}

__global__ void k_dis(const int* __restrict__ cnt, float* __restrict__ dis, int n) {
    int i = blockIdx.x * blockDim.x + threadIdx.x;
    if (i < n) dis[i] = rsqrtf((float)cnt[i] + 1.0f);
}

// Hierarchical exclusive scan: (1) per-1024-chunk local scan + chunk totals,
// (2) scan chunk totals (<=128 chunks), (3) add chunk offsets.
__global__ __launch_bounds__(256) void k_scan1(const int* __restrict__ cnt,
                                               int* __restrict__ loc,
                                               int* __restrict__ blk, int n) {
    __shared__ int s[256];
    int b = blockIdx.x, tid = threadIdx.x;
    int base = b * 1024 + tid * 4;
    int v0 = (base + 0 < n) ? cnt[base + 0] : 0;
    int v1 = (base + 1 < n) ? cnt[base + 1] : 0;
    int v2 = (base + 2 < n) ? cnt[base + 2] : 0;
    int v3 = (base + 3 < n) ? cnt[base + 3] : 0;
    int tsum = v0 + v1 + v2 + v3;
    s[tid] = tsum;
    __syncthreads();
    for (int off = 1; off < 256; off <<= 1) {
        int t = (tid >= off) ? s[tid - off] : 0;
        __syncthreads();
        s[tid] += t;
        __syncthreads();
    }
    int excl = s[tid] - tsum;
    if (base + 0 < n) loc[base + 0] = excl;
    if (base + 1 < n) loc[base + 1] = excl + v0;
    if (base + 2 < n) loc[base + 2] = excl + v0 + v1;
    if (base + 3 < n) loc[base + 3] = excl + v0 + v1 + v2;
    if (tid == 255) blk[b] = s[255];
}

__global__ __launch_bounds__(128) void k_scan2(int* __restrict__ blk, int nb,
                                               int* __restrict__ total_out) {
    __shared__ int s[128];
    int tid = threadIdx.x;
    int v = (tid < nb) ? blk[tid] : 0;
    s[tid] = v;
    __syncthreads();
    for (int off = 1; off < 128; off <<= 1) {
        int t = (tid >= off) ? s[tid - off] : 0;
        __syncthreads();
        s[tid] += t;
        __syncthreads();
    }
    if (tid < nb) blk[tid] = s[tid] - v;
    if (tid == 127) *total_out = s[127];
}

__global__ void k_scan3(int* __restrict__ row_off, const int* __restrict__ blk,
                        int* __restrict__ cursor, int n) {
    int i = blockIdx.x * blockDim.x + threadIdx.x;
    if (i < n) {
        int v = row_off[i] + blk[i >> 10];
        row_off[i] = v;
        cursor[i] = v;
    }
}

__global__ void k_reorder(const int* __restrict__ src, const int* __restrict__ dst,
                          int* __restrict__ cursor, int* __restrict__ col,
                          float* __restrict__ coefs, const float* __restrict__ dis, int E) {
    int e = blockIdx.x * blockDim.x + threadIdx.x;
    if (e < E) {
        int d = dst[e], s = src[e];
        int p = atomicAdd(&cursor[d], 1);
        col[p] = s;
        coefs[p] = dis[s] * dis[d];
    }
}

// H = X @ W (fp32 compute), output written as bf16 (message storage).
__global__ __launch_bounds__(256) void k_matmul(const float* __restrict__ X,
                                                const float* __restrict__ W,
                                                __hip_bfloat16* __restrict__ Hb, int n) {
    __shared__ float sX[64 * 128];
    const int tid = threadIdx.x;
    const int row0 = blockIdx.x * 64;
    for (int i = tid; i < 2048; i += 256) {
        int r = i >> 5;
        int gr = row0 + r;
        float4 v = make_float4(0.f, 0.f, 0.f, 0.f);
        if (gr < n) v = ((const float4*)(X + (size_t)gr * 128))[i & 31];
        ((float4*)sX)[i] = v;
    }
    __syncthreads();
    const int rg = tid >> 5;
    const int cg = tid & 31;
    const int r0 = rg * 8;
    const int c0 = cg * 4;
    float acc[8][4];
#pragma unroll
    for (int i = 0; i < 8; i++)
#pragma unroll
        for (int j = 0; j < 4; j++) acc[i][j] = 0.f;

    for (int k = 0; k < 128; k += 4) {
        float4 b0 = *(const float4*)(W + (size_t)(k + 0) * 128 + c0);
        float4 b1 = *(const float4*)(W + (size_t)(k + 1) * 128 + c0);
        float4 b2 = *(const float4*)(W + (size_t)(k + 2) * 128 + c0);
        float4 b3 = *(const float4*)(W + (size_t)(k + 3) * 128 + c0);
#pragma unroll
        for (int i = 0; i < 8; i++) {
            float4 a = *(const float4*)&sX[(r0 + i) * 128 + k];
            acc[i][0] += a.x * b0.x + a.y * b1.x + a.z * b2.x + a.w * b3.x;
            acc[i][1] += a.x * b0.y + a.y * b1.y + a.z * b2.y + a.w * b3.y;
            acc[i][2] += a.x * b0.z + a.y * b1.z + a.z * b2.z + a.w * b3.z;
            acc[i][3] += a.x * b0.w + a.y * b1.w + a.z * b2.w + a.w * b3.w;
        }
    }
#pragma unroll
    for (int i = 0; i < 8; i++) {
        int gr = row0 + r0 + i;
        if (gr < n) {
            union { bf2 h2[2]; uint2 u; } pk;
            pk.h2[0].x = __float2bfloat16(acc[i][0]);
            pk.h2[0].y = __float2bfloat16(acc[i][1]);
            pk.h2[1].x = __float2bfloat16(acc[i][2]);
            pk.h2[1].y = __float2bfloat16(acc[i][3]);
            *(uint2*)(Hb + (size_t)gr * 128 + c0) = pk.u;
        }
    }
}

// One wave (64 lanes) per node; lane l owns dims {2l, 2l+1}. CSR gather from
// bf16 messages, 4-way unrolled for memory-level parallelism; fused self-loop
// + bias + LayerNorm (+residual)(+relu). No __syncthreads needed.
__global__ __launch_bounds__(256) void k_node(const bf2* __restrict__ Hb,
                                              float* __restrict__ Xio,
                                              const int* __restrict__ row_off,
                                              const int* __restrict__ col,
                                              const float* __restrict__ coefs,
                                              const float* __restrict__ dis,
                                              const float* __restrict__ bias,
                                              const float* __restrict__ gamma,
                                              const float* __restrict__ beta,
                                              int do_relu, int do_res, int n) {
    const int wave = threadIdx.x >> 6;
    const int lane = threadIdx.x & 63;
    const int node = blockIdx.x * 4 + wave;
    if (node >= n) return;
    const int e0 = row_off[node];
    const int e1 = row_off[node + 1];
    float ax = 0.f, ay = 0.f;
    int e = e0;
    for (; e + 4 <= e1; e += 4) {
        int s0 = col[e], s1 = col[e + 1], s2 = col[e + 2], s3 = col[e + 3];
        float c0 = coefs[e], c1 = coefs[e + 1], c2 = coefs[e + 2], c3 = coefs[e + 3];
        bf2 v0 = Hb[(size_t)s0 * 64 + lane];
        bf2 v1 = Hb[(size_t)s1 * 64 + lane];
        bf2 v2 = Hb[(size_t)s2 * 64 + lane];
        bf2 v3 = Hb[(size_t)s3 * 64 + lane];
        ax += __bfloat162float(v0.x) * c0 + __bfloat162float(v1.x) * c1
            + __bfloat162float(v2.x) * c2 + __bfloat162float(v3.x) * c3;
        ay += __bfloat162float(v0.y) * c0 + __bfloat162float(v1.y) * c1
            + __bfloat162float(v2.y) * c2 + __bfloat162float(v3.y) * c3;
    }
    for (; e < e1; e++) {
        int s = col[e];
        float c = coefs[e];
        bf2 v = Hb[(size_t)s * 64 + lane];
        ax += __bfloat162float(v.x) * c;
        ay += __bfloat162float(v.y) * c;
    }
    float dn = dis[node];
    float dn2 = dn * dn;
    bf2 hv = Hb[(size_t)node * 64 + lane];
    ax += __bfloat162float(hv.x) * dn2;
    ay += __bfloat162float(hv.y) * dn2;
    float2 bb = *(const float2*)(bias + 2 * lane);
    ax += bb.x;
    ay += bb.y;

    // LayerNorm over 128 dims within one wave
    float t = ax + ay;
#pragma unroll
    for (int off = 32; off > 0; off >>= 1) t += __shfl_down(t, off, 64);
    float mu = __shfl(t, 0, 64) * (1.f / 128.f);
    float xmx = ax - mu, xmy = ay - mu;
    t = xmx * xmx + xmy * xmy;
#pragma unroll
    for (int off = 32; off > 0; off >>= 1) t += __shfl_down(t, off, 64);
    float var = __shfl(t, 0, 64) * (1.f / 128.f);
    float rs = rsqrtf(var + 1e-5f);
    float2 gg = *(const float2*)(gamma + 2 * lane);
    float2 be = *(const float2*)(beta + 2 * lane);
    float yx = xmx * rs * gg.x + be.x;
    float yy = xmy * rs * gg.y + be.y;
    if (do_res) {
        float2 r = *(const float2*)(Xio + (size_t)node * 128 + 2 * lane);
        yx += r.x;
        yy += r.y;
    }
    if (do_relu) {
        yx = fmaxf(yx, 0.f);
        yy = fmaxf(yy, 0.f);
    }
    *(float2*)(Xio + (size_t)node * 128 + 2 * lane) = make_float2(yx, yy);
}

// One 128-thread block per graph: binary-search segment in sorted batch,
// mean-pool, fused linear head.
__global__ __launch_bounds__(128) void k_pool(const float* __restrict__ X,
                                              const int* __restrict__ batch,
                                              const float* __restrict__ lin_w,
                                              const float* __restrict__ lin_b,
                                              float* __restrict__ out, int n) {
    int g = blockIdx.x;
    int d = threadIdx.x;
    int lo = 0, hi = n;
    while (lo < hi) { int m = (lo + hi) >> 1; if (batch[m] < g) lo = m + 1; else hi = m; }
    int start = lo;
    hi = n;
    while (lo < hi) { int m = (lo + hi) >> 1; if (batch[m] <= g) lo = m + 1; else hi = m; }
    int end = lo;
    float s = 0.f;
    for (int i = start; i < end; i++) s += X[(size_t)i * 128 + d];
    float cntf = (float)(end - start);
    float mean = s / fmaxf(cntf, 1.f);
    float p = mean * lin_w[d];
    __shared__ float red[2];
#pragma unroll
    for (int off = 32; off > 0; off >>= 1) p += __shfl_down(p, off, 64);
    if ((d & 63) == 0) red[d >> 6] = p;
    __syncthreads();
    if (d == 0) out[g] = red[0] + red[1] + lin_b[0];
}

extern "C" void kernel_launch(void* const* d_in, const int* in_sizes, int n_in,
                              void* d_out, int out_size, void* d_ws, size_t ws_size,
                              hipStream_t stream) {
    const float* x      = (const float*)d_in[0];
    const int*   eidx   = (const int*)d_in[1];
    const int*   batch  = (const int*)d_in[2];
    const float* Ws     = (const float*)d_in[3];
    const float* bs     = (const float*)d_in[4];
    const float* gammas = (const float*)d_in[5];
    const float* betas  = (const float*)d_in[6];
    const float* lin_w  = (const float*)d_in[7];
    const float* lin_b  = (const float*)d_in[8];
    float* out = (float*)d_out;

    const int n = in_sizes[2];        // 100000 nodes
    const int E = in_sizes[1] / 2;    // 1600000 edges
    const int G = out_size;           // 512 graphs
    const int nb = (n + 1023) / 1024; // scan chunks (<=128)

    const int* src  = eidx;
    const int* dstp = eidx + E;

    char* w = (char*)d_ws;
    size_t off = 0;
    auto alloc = [&](size_t bytes) {
        void* p = w + off;
        off = (off + bytes + 15) & ~(size_t)15;
        return p;
    };
    int*   cnt     = (int*)  alloc((size_t)n * 4);
    int*   row_off = (int*)  alloc((size_t)(n + 1) * 4);
    int*   cursor  = (int*)  alloc((size_t)n * 4);
    int*   blk     = (int*)  alloc(128 * 4);
    float* dis     = (float*)alloc((size_t)n * 4);
    int*   col     = (int*)  alloc((size_t)E * 4);
    float* coefs   = (float*)alloc((size_t)E * 4);
    __hip_bfloat16* hb = (__hip_bfloat16*)alloc((size_t)n * 128 * 2);
    float* xc      = (float*)alloc((size_t)n * 128 * 4);
    (void)ws_size; (void)n_in;

    hipMemsetAsync(cnt, 0, (size_t)n * 4, stream);
    k_hist<<<(E + 255) / 256, 256, 0, stream>>>(dstp, cnt, E);
    k_dis<<<(n + 255) / 256, 256, 0, stream>>>(cnt, dis, n);
    k_scan1<<<nb, 256, 0, stream>>>(cnt, row_off, blk, n);
    k_scan2<<<1, 128, 0, stream>>>(blk, nb, row_off + n);
    k_scan3<<<(n + 255) / 256, 256, 0, stream>>>(row_off, blk, cursor, n);
    k_reorder<<<(E + 255) / 256, 256, 0, stream>>>(src, dstp, cursor, col, coefs, dis, E);

    for (int layer = 0; layer < 4; layer++) {
        const float* xin = (layer == 0) ? x : xc;
        k_matmul<<<(n + 63) / 64, 256, 0, stream>>>(xin, Ws + (size_t)layer * 128 * 128, hb, n);
        k_node<<<(n + 3) / 4, 256, 0, stream>>>((const bf2*)hb, xc, row_off, col, coefs, dis,
                                                bs + (size_t)layer * 128,
                                                gammas + (size_t)layer * 128,
                                                betas + (size_t)layer * 128,
                                                (layer < 3) ? 1 : 0, (layer > 0) ? 1 : 0, n);
    }
    k_pool<<<G, 128, 0, stream>>>(xc, batch, lin_w, lin_b, out, n);
}

// Round 3
// 861.739 us; speedup vs baseline: 1.8018x; 1.0888x over previous
//
#include <hip/hip_runtime.h>
#include <hip/hip_bf16.h>

// ---------------------------------------------------------------------------
// MatGCN: 4-layer GCN (D=128) + LN + residual + mean-pool + linear head.
// R3: reorder writes col only (coef computed in k_node from dis),
//     MFMA bf16 matmul (padded LDS tiles, pre-transposed bf16 W).
// ---------------------------------------------------------------------------

typedef __hip_bfloat162 bf2;
typedef __attribute__((ext_vector_type(8))) short short8;
typedef __attribute__((ext_vector_type(4))) float f32x4;

__global__ void k_hist(const int* __restrict__ dst, int* __restrict__ cnt, int E) {
    int e = blockIdx.x * blockDim.x + threadIdx.x;
    if (e < E) atomicAdd(&cnt[dst[e]], 1);
}

__global__ void k_dis(const int* __restrict__ cnt, float* __restrict__ dis, int n) {
    int i = blockIdx.x * blockDim.x + threadIdx.x;
    if (i < n) dis[i] = rsqrtf((float)cnt[i] + 1.0f);
}

// Hierarchical exclusive scan
__global__ __launch_bounds__(256) void k_scan1(const int* __restrict__ cnt,
                                               int* __restrict__ loc,
                                               int* __restrict__ blk, int n) {
    __shared__ int s[256];
    int b = blockIdx.x, tid = threadIdx.x;
    int base = b * 1024 + tid * 4;
    int v0 = (base + 0 < n) ? cnt[base + 0] : 0;
    int v1 = (base + 1 < n) ? cnt[base + 1] : 0;
    int v2 = (base + 2 < n) ? cnt[base + 2] : 0;
    int v3 = (base + 3 < n) ? cnt[base + 3] : 0;
    int tsum = v0 + v1 + v2 + v3;
    s[tid] = tsum;
    __syncthreads();
    for (int off = 1; off < 256; off <<= 1) {
        int t = (tid >= off) ? s[tid - off] : 0;
        __syncthreads();
        s[tid] += t;
        __syncthreads();
    }
    int excl = s[tid] - tsum;
    if (base + 0 < n) loc[base + 0] = excl;
    if (base + 1 < n) loc[base + 1] = excl + v0;
    if (base + 2 < n) loc[base + 2] = excl + v0 + v1;
    if (base + 3 < n) loc[base + 3] = excl + v0 + v1 + v2;
    if (tid == 255) blk[b] = s[255];
}

__global__ __launch_bounds__(128) void k_scan2(int* __restrict__ blk, int nb,
                                               int* __restrict__ total_out) {
    __shared__ int s[128];
    int tid = threadIdx.x;
    int v = (tid < nb) ? blk[tid] : 0;
    s[tid] = v;
    __syncthreads();
    for (int off = 1; off < 128; off <<= 1) {
        int t = (tid >= off) ? s[tid - off] : 0;
        __syncthreads();
        s[tid] += t;
        __syncthreads();
    }
    if (tid < nb) blk[tid] = s[tid] - v;
    if (tid == 127) *total_out = s[127];
}

__global__ void k_scan3(int* __restrict__ row_off, const int* __restrict__ blk,
                        int* __restrict__ cursor, int n) {
    int i = blockIdx.x * blockDim.x + threadIdx.x;
    if (i < n) {
        int v = row_off[i] + blk[i >> 10];
        row_off[i] = v;
        cursor[i] = v;
    }
}

// col only — coef computed later in k_node (halves scattered write payload)
__global__ void k_reorder(const int* __restrict__ src, const int* __restrict__ dst,
                          int* __restrict__ cursor, int* __restrict__ col, int E) {
    int e = blockIdx.x * blockDim.x + threadIdx.x;
    if (e < E) {
        int d = dst[e], s = src[e];
        int p = atomicAdd(&cursor[d], 1);
        col[p] = s;
    }
}

// Wt[layer][c][k] = bf16(W[layer][k][c])
__global__ void k_prepw(const float* __restrict__ Ws, __hip_bfloat16* __restrict__ Wt) {
    int i = blockIdx.x * blockDim.x + threadIdx.x;  // 4*128*128
    int layer = i >> 14;
    int r = (i >> 7) & 127;   // output row = out-col of W
    int c = i & 127;          // output col = k
    Wt[i] = __float2bfloat16(Ws[layer * 16384 + c * 128 + r]);
}

// x (fp32) -> xb (bf16), layer-0 matmul input
__global__ void k_cvt(const float* __restrict__ X, __hip_bfloat16* __restrict__ Xb, int n128_4) {
    int i = blockIdx.x * blockDim.x + threadIdx.x;
    if (i < n128_4) {
        float4 v = ((const float4*)X)[i];
        union { bf2 h2[2]; uint2 u; } pk;
        pk.h2[0].x = __float2bfloat16(v.x);
        pk.h2[0].y = __float2bfloat16(v.y);
        pk.h2[1].x = __float2bfloat16(v.z);
        pk.h2[1].y = __float2bfloat16(v.w);
        ((uint2*)Xb)[i] = pk.u;
    }
}

// H = Xb @ W via mfma_f32_16x16x32_bf16. Block: 256 thr (4 waves), 64 rows.
// LDS: padded tiles (stride 136 bf16 = 272 B -> bank rotate 4/row, 2-way max).
__global__ __launch_bounds__(256) void k_matmul(const __hip_bfloat16* __restrict__ Xb,
                                                const __hip_bfloat16* __restrict__ Wt,
                                                __hip_bfloat16* __restrict__ Hb, int n) {
    __shared__ __align__(16) __hip_bfloat16 sX[64 * 136];
    __shared__ __align__(16) __hip_bfloat16 sW[128 * 136];
    const int tid = threadIdx.x;
    const int row0 = blockIdx.x * 64;
    for (int i = tid; i < 1024; i += 256) {          // X: 64x128 in 16B chunks
        int r = i >> 4, ck = i & 15;
        uint4 v = make_uint4(0, 0, 0, 0);
        int gr = row0 + r;
        if (gr < n) v = *(const uint4*)(Xb + (size_t)gr * 128 + ck * 8);
        *(uint4*)(sX + r * 136 + ck * 8) = v;
    }
    for (int i = tid; i < 2048; i += 256) {          // Wt: 128x128
        int r = i >> 4, ck = i & 15;
        uint4 v = *(const uint4*)(Wt + r * 128 + ck * 8);
        *(uint4*)(sW + r * 136 + ck * 8) = v;
    }
    __syncthreads();
    const int w = tid >> 6, l = tid & 63;
    const int quad = l >> 4, lr = l & 15;
    f32x4 acc[8];
#pragma unroll
    for (int c = 0; c < 8; c++) acc[c] = (f32x4){0.f, 0.f, 0.f, 0.f};
    short8 a[4];
#pragma unroll
    for (int kb = 0; kb < 4; kb++)
        a[kb] = *(const short8*)(sX + (w * 16 + lr) * 136 + kb * 32 + quad * 8);
#pragma unroll
    for (int c = 0; c < 8; c++) {
#pragma unroll
        for (int kb = 0; kb < 4; kb++) {
            short8 b = *(const short8*)(sW + (c * 16 + lr) * 136 + kb * 32 + quad * 8);
            acc[c] = __builtin_amdgcn_mfma_f32_16x16x32_bf16(a[kb], b, acc[c], 0, 0, 0);
        }
    }
    // epilogue: wave-private LDS transpose (reuse own sX rows) -> coalesced store
#pragma unroll
    for (int c = 0; c < 8; c++)
#pragma unroll
        for (int r = 0; r < 4; r++)
            sX[(w * 16 + quad * 4 + r) * 136 + c * 16 + lr] = __float2bfloat16(acc[c][r]);
#pragma unroll
    for (int p = 0; p < 4; p++) {
        int r = p * 4 + quad;
        int gr = row0 + w * 16 + r;
        uint4 v = *(const uint4*)(sX + (w * 16 + r) * 136 + lr * 8);
        if (gr < n) *(uint4*)(Hb + (size_t)gr * 128 + lr * 8) = v;
    }
}

// One wave per node: CSR gather of bf16 rows, coef = dis[s]*dis[node] computed
// in-kernel; fused self-loop + bias + LN (+res)(+relu). Dual-writes fp32 xc
// (residual stream) and bf16 xb (next matmul input).
__global__ __launch_bounds__(256) void k_node(const bf2* __restrict__ Hb,
                                              float* __restrict__ Xio,
                                              __hip_bfloat16* __restrict__ Xb,
                                              const int* __restrict__ row_off,
                                              const int* __restrict__ col,
                                              const float* __restrict__ dis,
                                              const float* __restrict__ bias,
                                              const float* __restrict__ gamma,
                                              const float* __restrict__ beta,
                                              int do_relu, int do_res, int write_xb, int n) {
    const int wave = threadIdx.x >> 6;
    const int lane = threadIdx.x & 63;
    const int node = blockIdx.x * 4 + wave;
    if (node >= n) return;
    const int e0 = row_off[node];
    const int e1 = row_off[node + 1];
    const float dn = dis[node];
    float ax = 0.f, ay = 0.f;
    int e = e0;
    for (; e + 4 <= e1; e += 4) {
        int s0 = col[e], s1 = col[e + 1], s2 = col[e + 2], s3 = col[e + 3];
        float c0 = dis[s0] * dn, c1 = dis[s1] * dn, c2 = dis[s2] * dn, c3 = dis[s3] * dn;
        bf2 v0 = Hb[(size_t)s0 * 64 + lane];
        bf2 v1 = Hb[(size_t)s1 * 64 + lane];
        bf2 v2 = Hb[(size_t)s2 * 64 + lane];
        bf2 v3 = Hb[(size_t)s3 * 64 + lane];
        ax += __bfloat162float(v0.x) * c0 + __bfloat162float(v1.x) * c1
            + __bfloat162float(v2.x) * c2 + __bfloat162float(v3.x) * c3;
        ay += __bfloat162float(v0.y) * c0 + __bfloat162float(v1.y) * c1
            + __bfloat162float(v2.y) * c2 + __bfloat162float(v3.y) * c3;
    }
    for (; e < e1; e++) {
        int s = col[e];
        float c = dis[s] * dn;
        bf2 v = Hb[(size_t)s * 64 + lane];
        ax += __bfloat162float(v.x) * c;
        ay += __bfloat162float(v.y) * c;
    }
    bf2 hv = Hb[(size_t)node * 64 + lane];
    float dn2 = dn * dn;
    ax += __bfloat162float(hv.x) * dn2;
    ay += __bfloat162float(hv.y) * dn2;
    float2 bb = *(const float2*)(bias + 2 * lane);
    ax += bb.x;
    ay += bb.y;

    float t = ax + ay;
#pragma unroll
    for (int off = 32; off > 0; off >>= 1) t += __shfl_down(t, off, 64);
    float mu = __shfl(t, 0, 64) * (1.f / 128.f);
    float xmx = ax - mu, xmy = ay - mu;
    t = xmx * xmx + xmy * xmy;
#pragma unroll
    for (int off = 32; off > 0; off >>= 1) t += __shfl_down(t, off, 64);
    float var = __shfl(t, 0, 64) * (1.f / 128.f);
    float rs = rsqrtf(var + 1e-5f);
    float2 gg = *(const float2*)(gamma + 2 * lane);
    float2 be = *(const float2*)(beta + 2 * lane);
    float yx = xmx * rs * gg.x + be.x;
    float yy = xmy * rs * gg.y + be.y;
    if (do_res) {
        float2 r = *(const float2*)(Xio + (size_t)node * 128 + 2 * lane);
        yx += r.x;
        yy += r.y;
    }
    if (do_relu) {
        yx = fmaxf(yx, 0.f);
        yy = fmaxf(yy, 0.f);
    }
    *(float2*)(Xio + (size_t)node * 128 + 2 * lane) = make_float2(yx, yy);
    if (write_xb) {
        bf2 o;
        o.x = __float2bfloat16(yx);
        o.y = __float2bfloat16(yy);
        ((bf2*)Xb)[(size_t)node * 64 + lane] = o;
    }
}

__global__ __launch_bounds__(128) void k_pool(const float* __restrict__ X,
                                              const int* __restrict__ batch,
                                              const float* __restrict__ lin_w,
                                              const float* __restrict__ lin_b,
                                              float* __restrict__ out, int n) {
    int g = blockIdx.x;
    int d = threadIdx.x;
    int lo = 0, hi = n;
    while (lo < hi) { int m = (lo + hi) >> 1; if (batch[m] < g) lo = m + 1; else hi = m; }
    int start = lo;
    hi = n;
    while (lo < hi) { int m = (lo + hi) >> 1; if (batch[m] <= g) lo = m + 1; else hi = m; }
    int end = lo;
    float s = 0.f;
    for (int i = start; i < end; i++) s += X[(size_t)i * 128 + d];
    float cntf = (float)(end - start);
    float mean = s / fmaxf(cntf, 1.f);
    float p = mean * lin_w[d];
    __shared__ float red[2];
#pragma unroll
    for (int off = 32; off > 0; off >>= 1) p += __shfl_down(p, off, 64);
    if ((d & 63) == 0) red[d >> 6] = p;
    __syncthreads();
    if (d == 0) out[g] = red[0] + red[1] + lin_b[0];
}

extern "C" void kernel_launch(void* const* d_in, const int* in_sizes, int n_in,
                              void* d_out, int out_size, void* d_ws, size_t ws_size,
                              hipStream_t stream) {
    const float* x      = (const float*)d_in[0];
    const int*   eidx   = (const int*)d_in[1];
    const int*   batch  = (const int*)d_in[2];
    const float* Ws     = (const float*)d_in[3];
    const float* bs     = (const float*)d_in[4];
    const float* gammas = (const float*)d_in[5];
    const float* betas  = (const float*)d_in[6];
    const float* lin_w  = (const float*)d_in[7];
    const float* lin_b  = (const float*)d_in[8];
    float* out = (float*)d_out;

    const int n = in_sizes[2];        // 100000
    const int E = in_sizes[1] / 2;    // 1600000
    const int G = out_size;           // 512
    const int nb = (n + 1023) / 1024;

    const int* src  = eidx;
    const int* dstp = eidx + E;

    char* w = (char*)d_ws;
    size_t off = 0;
    auto alloc = [&](size_t bytes) {
        void* p = w + off;
        off = (off + bytes + 15) & ~(size_t)15;
        return p;
    };
    int*   cnt     = (int*)  alloc((size_t)n * 4);
    int*   row_off = (int*)  alloc((size_t)(n + 1) * 4);
    int*   cursor  = (int*)  alloc((size_t)n * 4);
    int*   blk     = (int*)  alloc(128 * 4);
    float* dis     = (float*)alloc((size_t)n * 4);
    int*   col     = (int*)  alloc((size_t)E * 4);
    __hip_bfloat16* hb  = (__hip_bfloat16*)alloc((size_t)n * 128 * 2);
    __hip_bfloat16* xb  = (__hip_bfloat16*)alloc((size_t)n * 128 * 2);
    __hip_bfloat16* wt  = (__hip_bfloat16*)alloc((size_t)4 * 128 * 128 * 2);
    float* xc      = (float*)alloc((size_t)n * 128 * 4);
    (void)ws_size; (void)n_in;

    hipMemsetAsync(cnt, 0, (size_t)n * 4, stream);
    k_hist<<<(E + 255) / 256, 256, 0, stream>>>(dstp, cnt, E);
    k_dis<<<(n + 255) / 256, 256, 0, stream>>>(cnt, dis, n);
    k_scan1<<<nb, 256, 0, stream>>>(cnt, row_off, blk, n);
    k_scan2<<<1, 128, 0, stream>>>(blk, nb, row_off + n);
    k_scan3<<<(n + 255) / 256, 256, 0, stream>>>(row_off, blk, cursor, n);
    k_reorder<<<(E + 255) / 256, 256, 0, stream>>>(src, dstp, cursor, col, E);
    k_prepw<<<(4 * 128 * 128 + 255) / 256, 256, 0, stream>>>(Ws, wt);
    k_cvt<<<((n * 32) + 255) / 256, 256, 0, stream>>>(x, xb, n * 32);

    for (int layer = 0; layer < 4; layer++) {
        k_matmul<<<(n + 63) / 64, 256, 0, stream>>>(xb, wt + (size_t)layer * 16384, hb, n);
        k_node<<<(n + 3) / 4, 256, 0, stream>>>((const bf2*)hb, xc, xb, row_off, col, dis,
                                                bs + (size_t)layer * 128,
                                                gammas + (size_t)layer * 128,
                                                betas + (size_t)layer * 128,
                                                (layer < 3) ? 1 : 0, (layer > 0) ? 1 : 0,
                                                (layer < 3) ? 1 : 0, n);
    }
    k_pool<<<G, 128, 0, stream>>>(xc, batch, lin_w, lin_b, out, n);
}